// Round 1
// baseline (71.323 us; speedup 1.0000x reference)
//
#include <hip/hip_runtime.h>

#define NB 4
#define NGRID 512
#define NTARGET 1024
#define NBASIS 5
#define NCH 8
#define EPS_F 1e-6f
#define LOG2E 1.4426950408889634f
#define PAD_G 516  // NGRID+4; 516%32=4 -> c-groups land on disjoint bank sets

#if defined(__has_builtin)
#if __has_builtin(__builtin_amdgcn_exp2f)
#define EXP2F(x) __builtin_amdgcn_exp2f(x)
#else
#define EXP2F(x) exp2f(x)
#endif
#else
#define EXP2F(x) exp2f(x)
#endif

// Grid: NB*(NTARGET/4) = 1024 blocks, 256 threads.
//   b = blockIdx>>8, 4 targets/block, 8 channels, 8-way g-split (64 g/thread).
// Occupancy: LDS ~34 KB -> 4 blocks/CU = 16 waves/CU (4/SIMD, 50%) vs the
// previous 512-block config's 2/SIMD (25%). Latency-bound kernel -> 2x hiding.
// LDS layout transposed+padded [c][PAD_G]: per-thread g-walk is contiguous ->
// ds_read_b128 (2 instrs / 4 grid points, 4x fewer LDS issues). Bank check:
// 8 c-groups at word offsets c*516 (=4c mod 32) + 4g -> 32 disjoint banks;
// the two 64-g halves alias 2-way same-bank = free (m136).
// Fast path stores PRE-SCALED x (x * sqrt(0.5*log2e)/s) so the inner loop is
// d = x' - tx'; acc += w * exp2(-(d*d))  -- neg folds into v_exp modifier.
__global__ __launch_bounds__(256, 4) void final_layer_fused(
    const float* __restrict__ x_grid,   // (NB, NGRID, NCH)
    const float* __restrict__ h_grid,   // (NB, NGRID, NBASIS, NCH)
    const float* __restrict__ target_x, // (NB, NTARGET, NCH)
    const float* __restrict__ sigma,    // (NBASIS, NCH)
    const float* __restrict__ g_w,      // (1, NBASIS)
    const float* __restrict__ g_b,      // (1,)
    float* __restrict__ out)            // (NB, NTARGET, NCH)
{
    __shared__ float xs_t[NCH][PAD_G];  // 16.5 KB, scaled x, c-major
    __shared__ float hw_t[NCH][PAD_G];  // 16.5 KB, sum_k gw[k]*h[g,k,c]
    __shared__ float red[256];          // 1 KB partial buffer

    const int tid = threadIdx.x;
    const int c   = tid & 7;
    const int tt  = (tid >> 3) & 3;     // target within block
    const int gs  = tid >> 5;           // 0..7 g-split (64 g each)
    const int b   = blockIdx.x >> 8;
    const int t   = ((blockIdx.x & 255) << 2) + tt;

    // ---- phase 0: uniform-sigma check + scale (all scalar/uniform) ----
    int eq = 1;
    {
        const unsigned s0b = __float_as_uint(sigma[0]);
#pragma unroll
        for (int i = 1; i < NBASIS * NCH; ++i)
            eq &= (__float_as_uint(sigma[i]) == s0b);
    }
    const float sE = __expf(sigma[0]) + EPS_F;
    const float sc = eq ? (sqrtf(0.5f * LOG2E) / sE) : 1.0f;

    float gwv[NBASIS];
#pragma unroll
    for (int k = 0; k < NBASIS; ++k) gwv[k] = g_w[k];

    // ---- phase 1: staging, one g per thread per pass (vectorized) ----
    const float4* hb4 = reinterpret_cast<const float4*>(h_grid + (size_t)b * NGRID * NBASIS * NCH);
    const float4* xb4 = reinterpret_cast<const float4*>(x_grid + (size_t)b * NGRID * NCH);
#pragma unroll
    for (int j = 0; j < 2; ++j) {
        const int g = tid + j * 256;
        const float4* hp4 = hb4 + (size_t)g * 10;   // 40 floats = 10 float4 per g
        float4 hv[10];
#pragma unroll
        for (int q = 0; q < 10; ++q) hv[q] = hp4[q];
        const float* hf = reinterpret_cast<const float*>(hv);
        const float4 xa = xb4[g * 2];
        const float4 xb = xb4[g * 2 + 1];
        const float xv[8] = {xa.x, xa.y, xa.z, xa.w, xb.x, xb.y, xb.z, xb.w};
#pragma unroll
        for (int cc = 0; cc < 8; ++cc) {
            const float w = gwv[0] * hf[cc]      + gwv[1] * hf[8 + cc] +
                            gwv[2] * hf[16 + cc] + gwv[3] * hf[24 + cc] +
                            gwv[4] * hf[32 + cc];
            hw_t[cc][g] = w;
            xs_t[cc][g] = xv[cc] * sc;
        }
    }
    __syncthreads();

    // tx pre-scaled in eq path (sc=1 otherwise -> raw)
    const float tx = target_x[((size_t)b * NTARGET + t) * NCH + c] * sc;

    float p;
    if (eq) {
        // ---- fast path: 64 g, b128 LDS reads, 2-acc ILP ----
        const float* xp = &xs_t[c][gs * 64];
        const float* wp = &hw_t[c][gs * 64];
        float acc0 = 0.f, acc1 = 0.f;
#pragma unroll
        for (int q = 0; q < 16; ++q) {
            const float4 xv = *reinterpret_cast<const float4*>(xp + q * 4);
            const float4 wv = *reinterpret_cast<const float4*>(wp + q * 4);
            const float d0 = xv.x - tx;
            const float d1 = xv.y - tx;
            const float d2 = xv.z - tx;
            const float d3 = xv.w - tx;
            acc0 += wv.x * EXP2F(-(d0 * d0));
            acc1 += wv.y * EXP2F(-(d1 * d1));
            acc0 += wv.z * EXP2F(-(d2 * d2));
            acc1 += wv.w * EXP2F(-(d3 * d3));
        }
        p = acc0 + acc1;
    } else {
        // ---- general fallback (correctness only; sigma non-uniform) ----
        float coef[NBASIS];
#pragma unroll
        for (int k = 0; k < NBASIS; ++k) {
            const float s = __expf(sigma[k * NCH + c]) + EPS_F;
            coef[k] = -0.5f * LOG2E / (s * s);
        }
        const float* hg = h_grid + (size_t)b * NGRID * NBASIS * NCH + c;
        float acck[NBASIS] = {0.f, 0.f, 0.f, 0.f, 0.f};
        for (int gi = 0; gi < 64; ++gi) {
            const int g = gs * 64 + gi;
            const float d  = xs_t[c][g] - tx;   // sc==1 here: raw x
            const float d2 = d * d;
            const float* hpg = hg + (size_t)g * (NBASIS * NCH);
#pragma unroll
            for (int k = 0; k < NBASIS; ++k)
                acck[k] += hpg[k * NCH] * EXP2F(d2 * coef[k]);
        }
        p = 0.f;
#pragma unroll
        for (int k = 0; k < NBASIS; ++k) p += acck[k] * gwv[k];
    }

    // ---- epilogue: reduce 8 g-splits; 32 contiguous floats per block ----
    red[tid] = p;
    __syncthreads();
    if (tid < 32) {
        float r = g_b[0];
#pragma unroll
        for (int i = 0; i < 8; ++i) r += red[tid + 32 * i];
        out[((size_t)b * NTARGET + ((blockIdx.x & 255) << 2)) * NCH + tid] = r;
    }
}

extern "C" void kernel_launch(void* const* d_in, const int* in_sizes, int n_in,
                              void* d_out, int out_size, void* d_ws, size_t ws_size,
                              hipStream_t stream) {
    const float* x_grid   = (const float*)d_in[0];
    const float* h_grid   = (const float*)d_in[1];
    const float* target_x = (const float*)d_in[2];
    const float* sigma    = (const float*)d_in[3];
    const float* g_w      = (const float*)d_in[4];
    const float* g_b      = (const float*)d_in[5];
    float* out = (float*)d_out;

    final_layer_fused<<<NB * (NTARGET / 4), 256, 0, stream>>>(
        x_grid, h_grid, target_x, sigma, g_w, g_b, out);
}

// Round 2
// 70.173 us; speedup vs baseline: 1.0164x; 1.0164x over previous
//
#include <hip/hip_runtime.h>

#define NB 4
#define NGRID 512
#define NTARGET 1024
#define NBASIS 5
#define NCH 8
#define EPS_F 1e-6f
#define LOG2E 1.4426950408889634f

#if defined(__has_builtin)
#if __has_builtin(__builtin_amdgcn_exp2f)
#define EXP2F(x) __builtin_amdgcn_exp2f(x)
#else
#define EXP2F(x) exp2f(x)
#endif
#else
#define EXP2F(x) exp2f(x)
#endif

// No-LDS-staging variant (discriminating probe for H1 phase-serialization vs
// H2 overhead-floor). Grid: NB*(NTARGET/4) = 1024 blocks, 256 threads.
// Thread (c = tid&7, gs = tid>>3) owns a 16-g slice of the grid for ALL 4 of
// the block's targets. Inputs (520 KB) are L2-resident -> read h/x directly
// from global (each value read exactly once per block, same traffic as the
// old LDS staging but zero staging phase, zero big-LDS, zero pre-compute
// __syncthreads). Full unroll keeps g-offsets as load immediates (<= 2528 B).
// Inner math (uniform-sigma fast path), factored exponent:
//   -(x'-t')^2 = fma(2x', t', -x'^2) - t'^2  ->  per (g,t): fma + exp2 + fma,
// with exp2(-t'^2) applied once per target after the loop.
// Reduction: butterfly __shfl_xor over the 3 gs-bits inside each wave, then
// 4 partials per (t,c) through 512 B of LDS.
__global__ __launch_bounds__(256, 4) void final_layer_fused(
    const float* __restrict__ x_grid,   // (NB, NGRID, NCH)
    const float* __restrict__ h_grid,   // (NB, NGRID, NBASIS, NCH)
    const float* __restrict__ target_x, // (NB, NTARGET, NCH)
    const float* __restrict__ sigma,    // (NBASIS, NCH)
    const float* __restrict__ g_w,      // (1, NBASIS)
    const float* __restrict__ g_b,      // (1,)
    float* __restrict__ out)            // (NB, NTARGET, NCH)
{
    __shared__ float red[4][4][8];      // [wave][tt][c] = 512 B

    const int tid = threadIdx.x;
    const int c   = tid & 7;
    const int gs  = tid >> 3;           // 0..31, 16 g each
    const int w   = tid >> 6;           // wave 0..3
    const int b   = blockIdx.x >> 8;
    const int tbase = (blockIdx.x & 255) << 2;

    // sigma uniformity check (bitwise, uniform across threads)
    int eq = 1;
    {
        const unsigned s0b = __float_as_uint(sigma[0]);
#pragma unroll
        for (int i = 1; i < NBASIS * NCH; ++i)
            eq &= (__float_as_uint(sigma[i]) == s0b);
    }

    const float gw0 = g_w[0], gw1 = g_w[1], gw2 = g_w[2], gw3 = g_w[3], gw4 = g_w[4];

    const float* xp = x_grid + (size_t)b * NGRID * NCH + c;
    const float* hp = h_grid + (size_t)b * NGRID * NBASIS * NCH + c;
    const float* tp = target_x + ((size_t)b * NTARGET + tbase) * NCH + c;
    const int g0 = gs * (NGRID / 32);

    float acc0 = 0.f, acc1 = 0.f, acc2 = 0.f, acc3 = 0.f;

    if (eq) {
        const float sE = __expf(sigma[0]) + EPS_F;
        const float sc = sqrtf(0.5f * LOG2E) / sE;
        const float t0 = tp[0 * NCH] * sc;
        const float t1 = tp[1 * NCH] * sc;
        const float t2 = tp[2 * NCH] * sc;
        const float t3 = tp[3 * NCH] * sc;
        const float* xg = xp + (size_t)g0 * NCH;
        const float* hg = hp + (size_t)g0 * (NBASIS * NCH);
#pragma unroll
        for (int gi = 0; gi < 16; ++gi) {
            const float xv = xg[gi * NCH];
            const float* h = hg + gi * (NBASIS * NCH);
            const float hw = gw0 * h[0] + gw1 * h[8] + gw2 * h[16] +
                             gw3 * h[24] + gw4 * h[32];
            const float xq = xv * sc;
            const float a  = -(xq * xq);
            const float cg = xq + xq;
            acc0 += hw * EXP2F(fmaf(cg, t0, a));
            acc1 += hw * EXP2F(fmaf(cg, t1, a));
            acc2 += hw * EXP2F(fmaf(cg, t2, a));
            acc3 += hw * EXP2F(fmaf(cg, t3, a));
        }
        acc0 *= EXP2F(-(t0 * t0));
        acc1 *= EXP2F(-(t1 * t1));
        acc2 *= EXP2F(-(t2 * t2));
        acc3 *= EXP2F(-(t3 * t3));
    } else {
        // general fallback (sigma non-uniform): per-(k,c) coef, raw distances
        float coef[NBASIS];
#pragma unroll
        for (int k = 0; k < NBASIS; ++k) {
            const float s = __expf(sigma[k * NCH + c]) + EPS_F;
            coef[k] = -0.5f * LOG2E / (s * s);
        }
        const float t0 = tp[0 * NCH];
        const float t1 = tp[1 * NCH];
        const float t2 = tp[2 * NCH];
        const float t3 = tp[3 * NCH];
        const float* xg = xp + (size_t)g0 * NCH;
        const float* hg = hp + (size_t)g0 * (NBASIS * NCH);
        for (int gi = 0; gi < 16; ++gi) {
            const float xv = xg[gi * NCH];
            const float* h = hg + gi * (NBASIS * NCH);
            float hk[NBASIS];
            hk[0] = h[0]  * gw0;
            hk[1] = h[8]  * gw1;
            hk[2] = h[16] * gw2;
            hk[3] = h[24] * gw3;
            hk[4] = h[32] * gw4;
            {
                const float d = xv - t0, d2 = d * d;
                float s = 0.f;
#pragma unroll
                for (int k = 0; k < NBASIS; ++k) s += hk[k] * EXP2F(d2 * coef[k]);
                acc0 += s;
            }
            {
                const float d = xv - t1, d2 = d * d;
                float s = 0.f;
#pragma unroll
                for (int k = 0; k < NBASIS; ++k) s += hk[k] * EXP2F(d2 * coef[k]);
                acc1 += s;
            }
            {
                const float d = xv - t2, d2 = d * d;
                float s = 0.f;
#pragma unroll
                for (int k = 0; k < NBASIS; ++k) s += hk[k] * EXP2F(d2 * coef[k]);
                acc2 += s;
            }
            {
                const float d = xv - t3, d2 = d * d;
                float s = 0.f;
#pragma unroll
                for (int k = 0; k < NBASIS; ++k) s += hk[k] * EXP2F(d2 * coef[k]);
                acc3 += s;
            }
        }
    }

    // butterfly reduce over the 3 gs-bits inside each wave (lane bits 3,4,5)
#pragma unroll
    for (int off = 8; off < 64; off <<= 1) {
        acc0 += __shfl_xor(acc0, off);
        acc1 += __shfl_xor(acc1, off);
        acc2 += __shfl_xor(acc2, off);
        acc3 += __shfl_xor(acc3, off);
    }
    if ((tid & 63) < 8) {            // lane 0..7 -> c = lane
        red[w][0][c] = acc0;
        red[w][1][c] = acc1;
        red[w][2][c] = acc2;
        red[w][3][c] = acc3;
    }
    __syncthreads();
    if (tid < 32) {
        const int tt = tid >> 3;
        const int cc = tid & 7;
        const float r = g_b[0] + red[0][tt][cc] + red[1][tt][cc] +
                        red[2][tt][cc] + red[3][tt][cc];
        out[((size_t)b * NTARGET + tbase + tt) * NCH + cc] = r;
    }
}

extern "C" void kernel_launch(void* const* d_in, const int* in_sizes, int n_in,
                              void* d_out, int out_size, void* d_ws, size_t ws_size,
                              hipStream_t stream) {
    const float* x_grid   = (const float*)d_in[0];
    const float* h_grid   = (const float*)d_in[1];
    const float* target_x = (const float*)d_in[2];
    const float* sigma    = (const float*)d_in[3];
    const float* g_w      = (const float*)d_in[4];
    const float* g_b      = (const float*)d_in[5];
    float* out = (float*)d_out;

    final_layer_fused<<<NB * (NTARGET / 4), 256, 0, stream>>>(
        x_grid, h_grid, target_x, sigma, g_w, g_b, out);
}